// Round 5
// baseline (459.296 us; speedup 1.0000x reference)
//
#include <hip/hip_runtime.h>
#include <math.h>

typedef __attribute__((ext_vector_type(8))) short bf16x8;
typedef __attribute__((ext_vector_type(4))) float f32x4;
typedef __attribute__((ext_vector_type(4))) unsigned short u16x4;

#define NB 64
#define NS 4096
#define NH 512
#define NE 1024

__device__ __forceinline__ unsigned short f2bf(float f) {
  unsigned int u = __float_as_uint(f);
  u += 0x7fffu + ((u >> 16) & 1u);
  return (unsigned short)(u >> 16);
}

__device__ __forceinline__ float fast_tanh(float x) {
  float e = __expf(2.0f * x);
  return 1.0f - 2.0f * __builtin_amdgcn_rcpf(e + 1.0f);
}

// ---- pack W (f32 [512][1024]) into MFMA B-fragment order, bf16 ----
// chunk c = ((w*32 + kb)*4 + ni); lane l's 16B = W[w*64+ni*16+(l&15)][kb*32+(l>>4)*8 .. +7]
__global__ __launch_bounds__(256) void prep_b_kernel(const float* __restrict__ W,
                                                     unsigned short* __restrict__ Bp) {
  const int t = blockIdx.x * 256 + threadIdx.x;  // 0..65535
  const int lane = t & 63;
  const int ni = (t >> 6) & 3;
  const int kb = (t >> 8) & 31;
  const int w = t >> 13;
  const int col = w * 64 + ni * 16 + (lane & 15);
  const int k0 = kb * 32 + (lane >> 4) * 8;
  const float* src = W + col * NE + k0;
  float4 a = *(const float4*)src;
  float4 b = *(const float4*)(src + 4);
  union { bf16x8 v; unsigned short u[8]; } p;
  p.u[0] = f2bf(a.x); p.u[1] = f2bf(a.y); p.u[2] = f2bf(a.z); p.u[3] = f2bf(a.w);
  p.u[4] = f2bf(b.x); p.u[5] = f2bf(b.y); p.u[6] = f2bf(b.z); p.u[7] = f2bf(b.w);
  *(bf16x8*)(Bp + (long long)t * 8) = p.v;
}

// ---- prep: dec[b,h] = decoder_output[b,:] . W_s_w[h,:] + W_s_b[h] + W_h_b[h] ----
__global__ __launch_bounds__(512) void prep_dec_kernel(const float* __restrict__ dec,
                                                       const float* __restrict__ Wsw,
                                                       const float* __restrict__ Wsb,
                                                       const float* __restrict__ Whb,
                                                       float* __restrict__ decb) {
  int b = blockIdx.x;
  int h = threadIdx.x;
  const float4* dr = (const float4*)(dec + b * NH);
  const float4* wr = (const float4*)(Wsw + h * NH);
  float sum = Wsb[h] + Whb[h];
#pragma unroll 8
  for (int i = 0; i < NH / 4; ++i) {
    float4 a = dr[i], w = wr[i];
    sum += a.x * w.x + a.y * w.y + a.z * w.z + a.w * w.w;
  }
  decb[b * NH + h] = sum;
}

// ---- main: enc-proj GEMM (bf16 MFMA) + bias + tanh + v-dot -> scores ----
// BM=64, BN=512, BK=32, 512 thr / 8 waves, 2 blocks/CU.
// 4-phase K-step (m201 pattern): phase p = {mem issues | ds_read frag p ->
// lgkm -> cvt -> 4 MFMA}, 1 barrier/phase. Counted vmcnt, never 0 mid-loop (T4).
// A: f32 DMA 3-ahead into 4 rotating LDS buffers (both-sides XOR swizzle, G21).
// B: pre-packed frag order, L2 -> VGPR ping-pong (bA/bB), issued 1 step ahead.
__global__ __launch_bounds__(512, 4) void fused_main(const float* __restrict__ enc,
                                                     const unsigned short* __restrict__ Bp,
                                                     const float* __restrict__ decb,
                                                     const float* __restrict__ vw,
                                                     float* __restrict__ scores) {
  __shared__ __align__(16) float As[4][2048];  // 4 x 8KB: 64 rows x 32 f32, swizzled
  __shared__ float ssc[64];

  const int tid = threadIdx.x;
  const int lane = tid & 63;
  const int wave = tid >> 6;
  const int r15 = lane & 15;
  const int c4 = lane >> 4;
  const long long m0 = (long long)blockIdx.x * 64;

  if (tid < 64) ssc[tid] = 0.0f;

  // DMA staging: wave w lane l -> LDS bytes w*1024 + l*16 (linear); row w*8+(l>>3),
  // phys granule l&7; source granule pre-swizzled: (l&7)^(l>>3)
  const int grow = wave * 8 + (lane >> 3);
  const int ggran = (lane & 7) ^ (lane >> 3);
  const float* gsrc = enc + (m0 + grow) * NE + ggran * 4;
  const unsigned ldsoff = wave * 1024;  // bytes within each buffer

  // read-side: logical granule g at row r lives at phys g^(r&7); r&7 = lane&7
  const int rowb = r15 * 128;
  const int pg0 = (((c4 << 1) | 0) ^ (lane & 7)) << 4;
  const int pg1 = (((c4 << 1) | 1) ^ (lane & 7)) << 4;

  const unsigned short* const bb = Bp + (long long)wave * 32 * 2048 + lane * 8;

  f32x4 acc[4][4];
#pragma unroll
  for (int mi = 0; mi < 4; ++mi)
#pragma unroll
    for (int ni = 0; ni < 4; ++ni) {
      f32x4 z = {0.f, 0.f, 0.f, 0.f};
      acc[mi][ni] = z;
    }

  // prologue: DMA A(0),A(1),A(2) -> buffers 0,1,2; B(0) -> bA
  __builtin_amdgcn_global_load_lds((const unsigned int*)gsrc,
                                   (unsigned int*)((char*)&As[0][0] + ldsoff), 16, 0, 0);
  __builtin_amdgcn_global_load_lds((const unsigned int*)(gsrc + 32),
                                   (unsigned int*)((char*)&As[1][0] + ldsoff), 16, 0, 0);
  __builtin_amdgcn_global_load_lds((const unsigned int*)(gsrc + 64),
                                   (unsigned int*)((char*)&As[2][0] + ldsoff), 16, 0, 0);
  bf16x8 bA[4], bB[4];
#pragma unroll
  for (int ni = 0; ni < 4; ++ni) bA[ni] = *(const bf16x8*)(bb + ni * 512);

#pragma unroll
  for (int t = 0; t < 32; ++t) {
    const char* Ab = (const char*)&As[t & 3][0];
#pragma unroll
    for (int p = 0; p < 4; ++p) {
      bf16x8 af;
      if (p == 0) {
        // ---- mem issue phase: B(t+1) ping-pong, A(t+3) DMA ----
        if (t < 31) {
          const bf16x8* bp = (const bf16x8*)(bb + (t + 1) * 2048);
          if (t & 1) {
#pragma unroll
            for (int ni = 0; ni < 4; ++ni) bA[ni] = bp[ni * 64];
          } else {
#pragma unroll
            for (int ni = 0; ni < 4; ++ni) bB[ni] = bp[ni * 64];
          }
        }
        if (t < 29)
          __builtin_amdgcn_global_load_lds((const unsigned int*)(gsrc + (t + 3) * 32),
                                           (unsigned int*)((char*)&As[(t + 3) & 3][0] + ldsoff),
                                           16, 0, 0);
        // counted vmcnt: drain A(t) + B(t); keep newest prefetches in flight
        if (t == 0)       asm volatile("s_waitcnt vmcnt(5)" ::: "memory");
        else if (t < 29)  asm volatile("s_waitcnt vmcnt(6)" ::: "memory");
        else if (t == 29) asm volatile("s_waitcnt vmcnt(5)" ::: "memory");
        else if (t == 30) asm volatile("s_waitcnt vmcnt(4)" ::: "memory");
        else              asm volatile("s_waitcnt vmcnt(0)" ::: "memory");
        __builtin_amdgcn_s_barrier();  // DMA'd buffer t now visible to all waves
        f32x4 lo = *(const f32x4*)(Ab + rowb + pg0);
        f32x4 hi = *(const f32x4*)(Ab + rowb + pg1);
        asm volatile("s_waitcnt lgkmcnt(0)" ::: "memory");
        __builtin_amdgcn_sched_barrier(0);
        union { unsigned int u[4]; bf16x8 v; } pk;
        asm("v_cvt_pk_bf16_f32 %0, %1, %2" : "=v"(pk.u[0]) : "v"(lo.x), "v"(lo.y));
        asm("v_cvt_pk_bf16_f32 %0, %1, %2" : "=v"(pk.u[1]) : "v"(lo.z), "v"(lo.w));
        asm("v_cvt_pk_bf16_f32 %0, %1, %2" : "=v"(pk.u[2]) : "v"(hi.x), "v"(hi.y));
        asm("v_cvt_pk_bf16_f32 %0, %1, %2" : "=v"(pk.u[3]) : "v"(hi.z), "v"(hi.w));
        af = pk.v;
      } else {
        f32x4 lo = *(const f32x4*)(Ab + p * 2048 + rowb + pg0);
        f32x4 hi = *(const f32x4*)(Ab + p * 2048 + rowb + pg1);
        asm volatile("s_waitcnt lgkmcnt(0)" ::: "memory");
        __builtin_amdgcn_sched_barrier(0);
        union { unsigned int u[4]; bf16x8 v; } pk;
        asm("v_cvt_pk_bf16_f32 %0, %1, %2" : "=v"(pk.u[0]) : "v"(lo.x), "v"(lo.y));
        asm("v_cvt_pk_bf16_f32 %0, %1, %2" : "=v"(pk.u[1]) : "v"(lo.z), "v"(lo.w));
        asm("v_cvt_pk_bf16_f32 %0, %1, %2" : "=v"(pk.u[2]) : "v"(hi.x), "v"(hi.y));
        asm("v_cvt_pk_bf16_f32 %0, %1, %2" : "=v"(pk.u[3]) : "v"(hi.z), "v"(hi.w));
        af = pk.v;
        __builtin_amdgcn_s_barrier();  // phase rhythm (reads fenced by lgkm above)
      }
      __builtin_amdgcn_s_setprio(1);
      if (t & 1) {
#pragma unroll
        for (int ni = 0; ni < 4; ++ni)
          acc[p][ni] = __builtin_amdgcn_mfma_f32_16x16x32_bf16(af, bB[ni], acc[p][ni], 0, 0, 0);
      } else {
#pragma unroll
        for (int ni = 0; ni < 4; ++ni)
          acc[p][ni] = __builtin_amdgcn_mfma_f32_16x16x32_bf16(af, bA[ni], acc[p][ni], 0, 0, 0);
      }
      __builtin_amdgcn_s_setprio(0);
    }
  }

  // epilogue: x = tanh(acc + dec[b,h]); score += v[h]*x
  // C/D layout: col = lane&15 (n), row = (lane>>4)*4 + j (m)
  const int bidx = (int)(m0 >> 12);  // blockIdx / 64
  const float* decrow = decb + bidx * NH;
  float part[4][4];
#pragma unroll
  for (int mi = 0; mi < 4; ++mi)
#pragma unroll
    for (int j = 0; j < 4; ++j) part[mi][j] = 0.f;

#pragma unroll
  for (int ni = 0; ni < 4; ++ni) {
    int col = (wave << 6) + ni * 16 + r15;
    float vc = vw[col];
    float dc = decrow[col];
#pragma unroll
    for (int mi = 0; mi < 4; ++mi)
#pragma unroll
      for (int j = 0; j < 4; ++j)
        part[mi][j] += vc * fast_tanh(acc[mi][ni][j] + dc);
  }
#pragma unroll
  for (int off = 1; off < 16; off <<= 1)
#pragma unroll
    for (int mi = 0; mi < 4; ++mi)
#pragma unroll
      for (int j = 0; j < 4; ++j)
        part[mi][j] += __shfl_xor(part[mi][j], off, 64);

  if (r15 == 0) {
#pragma unroll
    for (int mi = 0; mi < 4; ++mi)
#pragma unroll
      for (int j = 0; j < 4; ++j)
        atomicAdd(&ssc[mi * 16 + c4 * 4 + j], part[mi][j]);
  }
  __syncthreads();
  if (tid < 64) scores[m0 + tid] = ssc[tid];
}

// ---- masked softmax over S per batch row ----
__global__ __launch_bounds__(1024) void softmax_kernel(const float* __restrict__ scores,
                                                       const int* __restrict__ mask,
                                                       float* __restrict__ out) {
  __shared__ float rmax[16];
  __shared__ float rsum[16];
  const int b = blockIdx.x;
  const int t = threadIdx.x;
  const int wid = t >> 6;
  const int ln = t & 63;
  const int base = b * NS;

  float s[4];
  int mk[4];
  float mx = -INFINITY;
#pragma unroll
  for (int i = 0; i < 4; ++i) {
    int idx = t + i * 1024;
    s[i] = scores[base + idx];
    mk[i] = mask[base + idx];
    if (mk[i]) mx = fmaxf(mx, s[i]);
  }
#pragma unroll
  for (int off = 1; off < 64; off <<= 1) mx = fmaxf(mx, __shfl_xor(mx, off, 64));
  if (ln == 0) rmax[wid] = mx;
  __syncthreads();
  float m2 = -INFINITY;
#pragma unroll
  for (int i = 0; i < 16; ++i) m2 = fmaxf(m2, rmax[i]);

  float e[4];
  float sum = 0.f;
#pragma unroll
  for (int i = 0; i < 4; ++i) {
    e[i] = mk[i] ? expf(s[i] - m2) : 0.f;
    sum += e[i];
  }
#pragma unroll
  for (int off = 1; off < 64; off <<= 1) sum += __shfl_xor(sum, off, 64);
  if (ln == 0) rsum[wid] = sum;
  __syncthreads();
  float tot = 0.f;
#pragma unroll
  for (int i = 0; i < 16; ++i) tot += rsum[i];
  float inv = 1.0f / tot;
#pragma unroll
  for (int i = 0; i < 4; ++i) {
    int idx = t + i * 1024;
    out[base + idx] = e[i] * inv;
  }
}

extern "C" void kernel_launch(void* const* d_in, const int* in_sizes, int n_in,
                              void* d_out, int out_size, void* d_ws, size_t ws_size,
                              hipStream_t stream) {
  const float* dec = (const float*)d_in[0];   // [64,512]
  const float* enc = (const float*)d_in[1];   // [64,4096,1024]
  const int* mask = (const int*)d_in[2];      // [64,4096]
  const float* Whw = (const float*)d_in[3];   // [512,1024]
  const float* Whb = (const float*)d_in[4];   // [512]
  const float* Wsw = (const float*)d_in[5];   // [512,512]
  const float* Wsb = (const float*)d_in[6];   // [512]
  const float* vw = (const float*)d_in[7];    // [1,512]
  float* out = (float*)d_out;                 // [64,4096]

  unsigned short* Bp = (unsigned short*)d_ws;                         // 1 MB packed W
  float* decb = (float*)((char*)d_ws + (1 << 20));                    // 128 KB
  float* scoresb = (float*)((char*)d_ws + (1 << 20) + (128 << 10));   // 1 MB

  prep_b_kernel<<<dim3(256), dim3(256), 0, stream>>>(Whw, Bp);
  prep_dec_kernel<<<dim3(64), dim3(512), 0, stream>>>(dec, Wsw, Wsb, Whb, decb);
  fused_main<<<dim3(4096), dim3(512), 0, stream>>>(enc, Bp, decb, vw, scoresb);
  softmax_kernel<<<dim3(64), dim3(1024), 0, stream>>>(scoresb, mask, out);
}

// Round 6
// 385.136 us; speedup vs baseline: 1.1926x; 1.1926x over previous
//
#include <hip/hip_runtime.h>
#include <math.h>

typedef __attribute__((ext_vector_type(8))) short bf16x8;
typedef __attribute__((ext_vector_type(4))) float f32x4;
typedef __attribute__((ext_vector_type(4))) unsigned short u16x4;

#define NB 64
#define NS 4096
#define NH 512
#define NE 1024
#define APITCH 80  // 64B bf16 K-row + 16B pad: conflict-free b128 frag reads

__device__ __forceinline__ unsigned short f2bf(float f) {
  unsigned int u = __float_as_uint(f);
  u += 0x7fffu + ((u >> 16) & 1u);
  return (unsigned short)(u >> 16);
}

__device__ __forceinline__ float fast_tanh(float x) {
  float e = __expf(2.0f * x);
  return 1.0f - 2.0f * __builtin_amdgcn_rcpf(e + 1.0f);
}

// ---- pack W (f32 [512][1024]) into MFMA B-fragment order, bf16 ----
// chunk c = ((w*32 + kb)*4 + ni); lane l's 16B = W[w*64+ni*16+(l&15)][kb*32+(l>>4)*8 .. +7]
__global__ __launch_bounds__(256) void prep_b_kernel(const float* __restrict__ W,
                                                     unsigned short* __restrict__ Bp) {
  const int t = blockIdx.x * 256 + threadIdx.x;  // 0..65535
  const int lane = t & 63;
  const int ni = (t >> 6) & 3;
  const int kb = (t >> 8) & 31;
  const int w = t >> 13;
  const int col = w * 64 + ni * 16 + (lane & 15);
  const int k0 = kb * 32 + (lane >> 4) * 8;
  const float* src = W + col * NE + k0;
  float4 a = *(const float4*)src;
  float4 b = *(const float4*)(src + 4);
  union { bf16x8 v; unsigned short u[8]; } p;
  p.u[0] = f2bf(a.x); p.u[1] = f2bf(a.y); p.u[2] = f2bf(a.z); p.u[3] = f2bf(a.w);
  p.u[4] = f2bf(b.x); p.u[5] = f2bf(b.y); p.u[6] = f2bf(b.z); p.u[7] = f2bf(b.w);
  *(bf16x8*)(Bp + (long long)t * 8) = p.v;
}

// ---- prep: dec[b,h] = decoder_output[b,:] . W_s_w[h,:] + W_s_b[h] + W_h_b[h] ----
__global__ __launch_bounds__(512) void prep_dec_kernel(const float* __restrict__ dec,
                                                       const float* __restrict__ Wsw,
                                                       const float* __restrict__ Wsb,
                                                       const float* __restrict__ Whb,
                                                       float* __restrict__ decb) {
  int b = blockIdx.x;
  int h = threadIdx.x;
  const float4* dr = (const float4*)(dec + b * NH);
  const float4* wr = (const float4*)(Wsw + h * NH);
  float sum = Wsb[h] + Whb[h];
#pragma unroll 8
  for (int i = 0; i < NH / 4; ++i) {
    float4 a = dr[i], w = wr[i];
    sum += a.x * w.x + a.y * w.y + a.z * w.z + a.w * w.w;
  }
  decb[b * NH + h] = sum;
}

// ---- main: enc-proj GEMM (bf16 MFMA) + bias + tanh + v-dot -> scores ----
// BM=64, BN=512, BK=32, 512 thr / 8 waves, 2 blocks/CU (<=128 regs).
// A: global float4 -> regs (1 step ahead) -> cvt_pk bf16 -> ds_write_b64 into
//    2x5KB double buffer (80B pitch). LDS read = 4x ds_read_b128 / wave / step.
// B: pre-packed frag order, L2 -> bcur right after MFMA cluster (compiler vmcnt).
// Sync: ONE raw s_barrier + lgkmcnt(0) per K-step; all other waits compiler-counted.
__global__ __launch_bounds__(512, 4) void fused_main(const float* __restrict__ enc,
                                                     const unsigned short* __restrict__ Bp,
                                                     const float* __restrict__ decb,
                                                     const float* __restrict__ vw,
                                                     float* __restrict__ scores) {
  __shared__ __align__(16) char As[2][64 * APITCH];  // bf16 tiles, 2 x 5KB
  __shared__ float ssc[64];

  const int tid = threadIdx.x;
  const int lane = tid & 63;
  const int wave = tid >> 6;
  const int r15 = lane & 15;
  const int c4 = lane >> 4;
  const long long m0 = (long long)blockIdx.x * 64;

  if (tid < 64) ssc[tid] = 0.0f;

  // A staging: thread t -> row t>>3, f32-chunk t&7 (4 floats, coalesced 128B/row)
  const int arow = tid >> 3;
  const int achk = tid & 7;
  const float* aload = enc + (m0 + arow) * NE + achk * 4;
  const int awr = arow * APITCH + achk * 8;  // bf16 bytes

  // B packed base for this wave
  const unsigned short* const bb = Bp + (long long)wave * 32 * 2048 + lane * 8;

  f32x4 acc[4][4];
#pragma unroll
  for (int mi = 0; mi < 4; ++mi)
#pragma unroll
    for (int ni = 0; ni < 4; ++ni) {
      f32x4 z = {0.f, 0.f, 0.f, 0.f};
      acc[mi][ni] = z;
    }

  // prologue: B(0)->bcur; A(0)->cvt->buf0; A(1)->aCur
  bf16x8 bcur[4];
#pragma unroll
  for (int ni = 0; ni < 4; ++ni) bcur[ni] = *(const bf16x8*)(bb + ni * 512);
  {
    float4 a0 = *(const float4*)(aload);
    unsigned int p0, p1;
    asm("v_cvt_pk_bf16_f32 %0, %1, %2" : "=v"(p0) : "v"(a0.x), "v"(a0.y));
    asm("v_cvt_pk_bf16_f32 %0, %1, %2" : "=v"(p1) : "v"(a0.z), "v"(a0.w));
    uint2 wv; wv.x = p0; wv.y = p1;
    *(uint2*)(&As[0][0] + awr) = wv;
  }
  float4 aCur = *(const float4*)(aload + 32);  // A(1)
  asm volatile("s_waitcnt lgkmcnt(0)" ::: "memory");
  __builtin_amdgcn_s_barrier();
  __builtin_amdgcn_sched_barrier(0);

#pragma unroll
  for (int t = 0; t < 32; ++t) {
    const char* Ab = &As[t & 1][0];
    // issue A(t+2) early (HBM; consumed next step's write phase)
    float4 aNew;
    if (t < 30) aNew = *(const float4*)(aload + (t + 2) * 32);
    // frag reads (bf16, conflict-free at 80B pitch); compiler emits counted lgkm
    bf16x8 af[4];
#pragma unroll
    for (int mi = 0; mi < 4; ++mi)
      af[mi] = *(const bf16x8*)(Ab + (mi * 16 + r15) * APITCH + c4 * 16);
    __builtin_amdgcn_s_setprio(1);
#pragma unroll
    for (int mi = 0; mi < 4; ++mi)
#pragma unroll
      for (int ni = 0; ni < 4; ++ni)
        acc[mi][ni] = __builtin_amdgcn_mfma_f32_16x16x32_bf16(af[mi], bcur[ni],
                                                              acc[mi][ni], 0, 0, 0);
    __builtin_amdgcn_s_setprio(0);
    // B(t+1) reload (WAR on MFMAs keeps these after the cluster; vmcnt counted)
    if (t < 31) {
      const bf16x8* bp = (const bf16x8*)(bb + (t + 1) * 2048);
#pragma unroll
      for (int ni = 0; ni < 4; ++ni) bcur[ni] = bp[ni * 64];
    }
    // write A(t+1) -> opposite buffer (aCur loaded one step ago; vmcnt counted)
    if (t < 31) {
      unsigned int p0, p1;
      asm("v_cvt_pk_bf16_f32 %0, %1, %2" : "=v"(p0) : "v"(aCur.x), "v"(aCur.y));
      asm("v_cvt_pk_bf16_f32 %0, %1, %2" : "=v"(p1) : "v"(aCur.z), "v"(aCur.w));
      uint2 wv; wv.x = p0; wv.y = p1;
      *(uint2*)(&As[(t & 1) ^ 1][0] + awr) = wv;
      aCur = aNew;
    }
    // one barrier per K-step: reads of buf[t&1] + write of buf[t&1^1] both fenced
    asm volatile("s_waitcnt lgkmcnt(0)" ::: "memory");
    __builtin_amdgcn_sched_barrier(0);
    __builtin_amdgcn_s_barrier();
  }

  // epilogue: x = tanh(acc + dec[b,h]); score += v[h]*x
  // C/D layout: col = lane&15 (n), row = (lane>>4)*4 + j (m)
  const int bidx = (int)(m0 >> 12);  // blockIdx / 64
  const float* decrow = decb + bidx * NH;
  float part[4][4];
#pragma unroll
  for (int mi = 0; mi < 4; ++mi)
#pragma unroll
    for (int j = 0; j < 4; ++j) part[mi][j] = 0.f;

#pragma unroll
  for (int ni = 0; ni < 4; ++ni) {
    int col = (wave << 6) + ni * 16 + r15;
    float vc = vw[col];
    float dc = decrow[col];
#pragma unroll
    for (int mi = 0; mi < 4; ++mi)
#pragma unroll
      for (int j = 0; j < 4; ++j)
        part[mi][j] += vc * fast_tanh(acc[mi][ni][j] + dc);
  }
#pragma unroll
  for (int off = 1; off < 16; off <<= 1)
#pragma unroll
    for (int mi = 0; mi < 4; ++mi)
#pragma unroll
      for (int j = 0; j < 4; ++j)
        part[mi][j] += __shfl_xor(part[mi][j], off, 64);

  if (r15 == 0) {
#pragma unroll
    for (int mi = 0; mi < 4; ++mi)
#pragma unroll
      for (int j = 0; j < 4; ++j)
        atomicAdd(&ssc[mi * 16 + c4 * 4 + j], part[mi][j]);
  }
  __syncthreads();
  if (tid < 64) scores[m0 + tid] = ssc[tid];
}

// ---- masked softmax over S per batch row ----
__global__ __launch_bounds__(1024) void softmax_kernel(const float* __restrict__ scores,
                                                       const int* __restrict__ mask,
                                                       float* __restrict__ out) {
  __shared__ float rmax[16];
  __shared__ float rsum[16];
  const int b = blockIdx.x;
  const int t = threadIdx.x;
  const int wid = t >> 6;
  const int ln = t & 63;
  const int base = b * NS;

  float s[4];
  int mk[4];
  float mx = -INFINITY;
#pragma unroll
  for (int i = 0; i < 4; ++i) {
    int idx = t + i * 1024;
    s[i] = scores[base + idx];
    mk[i] = mask[base + idx];
    if (mk[i]) mx = fmaxf(mx, s[i]);
  }
#pragma unroll
  for (int off = 1; off < 64; off <<= 1) mx = fmaxf(mx, __shfl_xor(mx, off, 64));
  if (ln == 0) rmax[wid] = mx;
  __syncthreads();
  float m2 = -INFINITY;
#pragma unroll
  for (int i = 0; i < 16; ++i) m2 = fmaxf(m2, rmax[i]);

  float e[4];
  float sum = 0.f;
#pragma unroll
  for (int i = 0; i < 4; ++i) {
    e[i] = mk[i] ? expf(s[i] - m2) : 0.f;
    sum += e[i];
  }
#pragma unroll
  for (int off = 1; off < 64; off <<= 1) sum += __shfl_xor(sum, off, 64);
  if (ln == 0) rsum[wid] = sum;
  __syncthreads();
  float tot = 0.f;
#pragma unroll
  for (int i = 0; i < 16; ++i) tot += rsum[i];
  float inv = 1.0f / tot;
#pragma unroll
  for (int i = 0; i < 4; ++i) {
    int idx = t + i * 1024;
    out[base + idx] = e[i] * inv;
  }
}

extern "C" void kernel_launch(void* const* d_in, const int* in_sizes, int n_in,
                              void* d_out, int out_size, void* d_ws, size_t ws_size,
                              hipStream_t stream) {
  const float* dec = (const float*)d_in[0];   // [64,512]
  const float* enc = (const float*)d_in[1];   // [64,4096,1024]
  const int* mask = (const int*)d_in[2];      // [64,4096]
  const float* Whw = (const float*)d_in[3];   // [512,1024]
  const float* Whb = (const float*)d_in[4];   // [512]
  const float* Wsw = (const float*)d_in[5];   // [512,512]
  const float* Wsb = (const float*)d_in[6];   // [512]
  const float* vw = (const float*)d_in[7];    // [1,512]
  float* out = (float*)d_out;                 // [64,4096]

  unsigned short* Bp = (unsigned short*)d_ws;                         // 1 MB packed W
  float* decb = (float*)((char*)d_ws + (1 << 20));                    // 128 KB
  float* scoresb = (float*)((char*)d_ws + (1 << 20) + (128 << 10));   // 1 MB

  prep_b_kernel<<<dim3(256), dim3(256), 0, stream>>>(Whw, Bp);
  prep_dec_kernel<<<dim3(64), dim3(512), 0, stream>>>(dec, Wsw, Wsb, Whb, decb);
  fused_main<<<dim3(4096), dim3(512), 0, stream>>>(enc, Bp, decb, vw, scoresb);
  softmax_kernel<<<dim3(64), dim3(1024), 0, stream>>>(scoresb, mask, out);
}